// Round 1
// baseline (3710.501 us; speedup 1.0000x reference)
//
#include <hip/hip_runtime.h>
#include <math.h>

// ---------------- helpers ----------------
__device__ __forceinline__ void ld16(const float* __restrict__ p, float* a) {
    const float4* q = (const float4*)p;
    float4 v0 = q[0], v1 = q[1], v2 = q[2], v3 = q[3];
    a[0]=v0.x; a[1]=v0.y; a[2]=v0.z; a[3]=v0.w;
    a[4]=v1.x; a[5]=v1.y; a[6]=v1.z; a[7]=v1.w;
    a[8]=v2.x; a[9]=v2.y; a[10]=v2.z; a[11]=v2.w;
    a[12]=v3.x; a[13]=v3.y; a[14]=v3.z; a[15]=v3.w;
}

// ---------------- decoder weight transpose (once) ----------------
__global__ void k_prep(const float* __restrict__ dw0, const float* __restrict__ dw1,
                       const float* __restrict__ dw2, const float* __restrict__ dw3,
                       const float* __restrict__ dw4, float* __restrict__ t) {
    int i = blockIdx.x * blockDim.x + threadIdx.x;
    if (i < 2048)       { int r = i / 64, c = i % 64;          t[c*32 + r]          = dw0[i]; }
    else if (i < 6144)  { int j = i - 2048;  int r=j/64,c=j%64; t[2048  + c*64 + r] = dw1[j]; }
    else if (i < 10240) { int j = i - 6144;  int r=j/64,c=j%64; t[6144  + c*64 + r] = dw2[j]; }
    else if (i < 14336) { int j = i - 10240; int r=j/64,c=j%64; t[10240 + c*64 + r] = dw3[j]; }
    else if (i < 14848) { int j = i - 14336; int r=j/8, c=j%8;  t[14336 + c*64 + r] = dw4[j]; }
}

// ---------------- conv edge kernel: msg + atomic scatter ----------------
__global__ __launch_bounds__(256) void k_conv(
    const float* __restrict__ h, const int* __restrict__ ei,
    const float* __restrict__ ea,
    const float* __restrict__ w1, const float* __restrict__ b1,
    const float* __restrict__ w2, const float* __restrict__ b2,
    float* __restrict__ agg, int E)
{
    int t = blockIdx.x * blockDim.x + threadIdx.x;
    int e0 = t * 2;
    if (e0 >= E) return;
    int e1 = e0 + 1;                       // E is even

    int s0 = ei[e0], s1 = ei[e1];
    int d0 = ei[E + e0], d1 = ei[E + e1];

    // edge_attr rows (8 floats each)
    float ea0[8], ea1[8];
    {
        const float4* p = (const float4*)(ea + (size_t)e0 * 8);
        float4 v0 = p[0], v1 = p[1];
        ea0[0]=v0.x; ea0[1]=v0.y; ea0[2]=v0.z; ea0[3]=v0.w;
        ea0[4]=v1.x; ea0[5]=v1.y; ea0[6]=v1.z; ea0[7]=v1.w;
        const float4* q = (const float4*)(ea + (size_t)e1 * 8);
        float4 u0 = q[0], u1 = q[1];
        ea1[0]=u0.x; ea1[1]=u0.y; ea1[2]=u0.z; ea1[3]=u0.w;
        ea1[4]=u1.x; ea1[5]=u1.y; ea1[6]=u1.z; ea1[7]=u1.w;
    }

    float h0[16], h1[16];
    ld16(h + (size_t)s0 * 16, h0);
    ld16(h + (size_t)s1 * 16, h1);

    float m0[16], m1[16];
    #pragma unroll
    for (int q = 0; q < 16; q++) { m0[q] = 0.f; m1[q] = 0.f; }

    // msg[o] = sum_i hsrc[i] * ( b2[i*16+o] + sum_k hid[k]*w2[k*256+i*16+o] )
    #pragma unroll 1
    for (int k = 0; k < 16; k++) {
        float bk = b1[k];
        float a0 = bk, a1 = bk;
        #pragma unroll
        for (int j = 0; j < 8; j++) {
            float w = w1[j * 16 + k];
            a0 += ea0[j] * w;
            a1 += ea1[j] * w;
        }
        a0 = fmaxf(a0, 0.f);
        a1 = fmaxf(a1, 0.f);
        const float4* w4 = (const float4*)(w2 + k * 256);
        #pragma unroll
        for (int i = 0; i < 16; i++) {
            float s0v = a0 * h0[i];
            float s1v = a1 * h1[i];
            #pragma unroll
            for (int q = 0; q < 4; q++) {
                float4 w = w4[i * 4 + q];
                m0[q*4+0] += s0v * w.x; m0[q*4+1] += s0v * w.y;
                m0[q*4+2] += s0v * w.z; m0[q*4+3] += s0v * w.w;
                m1[q*4+0] += s1v * w.x; m1[q*4+1] += s1v * w.y;
                m1[q*4+2] += s1v * w.z; m1[q*4+3] += s1v * w.w;
            }
        }
    }
    // b2 term
    {
        const float4* b4 = (const float4*)b2;
        #pragma unroll
        for (int i = 0; i < 16; i++) {
            float s0v = h0[i];
            float s1v = h1[i];
            #pragma unroll
            for (int q = 0; q < 4; q++) {
                float4 w = b4[i * 4 + q];
                m0[q*4+0] += s0v * w.x; m0[q*4+1] += s0v * w.y;
                m0[q*4+2] += s0v * w.z; m0[q*4+3] += s0v * w.w;
                m1[q*4+0] += s1v * w.x; m1[q*4+1] += s1v * w.y;
                m1[q*4+2] += s1v * w.z; m1[q*4+3] += s1v * w.w;
            }
        }
    }

    #pragma unroll
    for (int q = 0; q < 16; q++) atomicAdd(&agg[(size_t)d0 * 16 + q], m0[q]);
    #pragma unroll
    for (int q = 0; q < 16; q++) atomicAdd(&agg[(size_t)d1 * 16 + q], m1[q]);
}

// ---------------- node update: root weight + bias + relu + BN stats ----------------
__global__ __launch_bounds__(256) void k_node(
    const float* __restrict__ h, const float* __restrict__ agg,
    const float* __restrict__ root, const float* __restrict__ cb,
    float* __restrict__ h2, float* __restrict__ stats, int N)
{
    int t = blockIdx.x * blockDim.x + threadIdx.x;
    int n = t >> 4;
    int o = t & 15;
    float v = 0.f;
    if (n < N) {
        v = agg[(size_t)n * 16 + o] + cb[o];
        float hr[16];
        ld16(h + (size_t)n * 16, hr);
        #pragma unroll
        for (int i = 0; i < 16; i++) v += hr[i] * root[i * 16 + o];
        v = fmaxf(v, 0.f);
        h2[(size_t)n * 16 + o] = v;
    }
    __shared__ float ls[256];
    __shared__ float ls2[256];
    int tid = threadIdx.x;
    ls[tid] = v;
    ls2[tid] = v * v;
    __syncthreads();
    #pragma unroll
    for (int s = 128; s >= 16; s >>= 1) {
        if (tid < s) { ls[tid] += ls[tid + s]; ls2[tid] += ls2[tid + s]; }
        __syncthreads();
    }
    if (tid < 16) {
        atomicAdd(&stats[tid], ls[tid]);
        atomicAdd(&stats[16 + tid], ls2[tid]);
    }
}

// ---------------- BN apply ----------------
__global__ __launch_bounds__(256) void k_bn(
    const float* __restrict__ h2, const float* __restrict__ stats,
    const float* __restrict__ g, const float* __restrict__ be,
    float* __restrict__ hout, int N, float invN)
{
    int t = blockIdx.x * blockDim.x + threadIdx.x;
    if (t >= N * 16) return;
    int o = t & 15;
    float m = stats[o] * invN;
    float var = stats[16 + o] * invN - m * m;
    float sc = g[o] * rsqrtf(var + 1e-5f);
    hout[t] = (h2[t] - m) * sc + be[o];
}

// ---------------- mu / logvar / reparameterize ----------------
__global__ __launch_bounds__(256) void k_z(
    const float* __restrict__ h, const float* __restrict__ mu_w, const float* __restrict__ mu_b,
    const float* __restrict__ lv_w, const float* __restrict__ lv_b,
    const float* __restrict__ eps, float* __restrict__ z, int N)
{
    int t = blockIdx.x * blockDim.x + threadIdx.x;
    if (t >= N * 16) return;
    int n = t >> 4;
    int o = t & 15;
    float hr[16];
    ld16(h + (size_t)n * 16, hr);
    float mu = mu_b[o];
    float lv = lv_b[o];
    #pragma unroll
    for (int i = 0; i < 16; i++) {
        mu += hr[i] * mu_w[i * 16 + o];
        lv += hr[i] * lv_w[i * 16 + o];
    }
    lv = fminf(lv, 10.f);
    z[t] = mu + eps[t] * expf(0.5f * lv);
}

// ---------------- decoder ----------------
__device__ __forceinline__ void dec_layer64(const float* __restrict__ wt,
                                            const float* __restrict__ bias,
                                            float* lbase, int lane)
{
    float a[64];
    #pragma unroll
    for (int q = 0; q < 16; q++) {
        float4 v = *(const float4*)(lbase + ((q ^ lane) << 2));
        a[q*4+0]=v.x; a[q*4+1]=v.y; a[q*4+2]=v.z; a[q*4+3]=v.w;
    }
    #pragma unroll 2
    for (int o = 0; o < 64; o++) {
        float acc = bias[o];
        const float4* w = (const float4*)(wt + o * 64);
        #pragma unroll
        for (int q = 0; q < 16; q++) {
            float4 wv = w[q];
            acc += a[q*4+0]*wv.x + a[q*4+1]*wv.y + a[q*4+2]*wv.z + a[q*4+3]*wv.w;
        }
        lbase[(((o >> 2) ^ lane) << 2) | (o & 3)] = fmaxf(acc, 0.f);
    }
}

__global__ __launch_bounds__(128) void k_dec(
    const float* __restrict__ z, const int* __restrict__ ei,
    const float* __restrict__ decw,
    const float* __restrict__ db0, const float* __restrict__ db1,
    const float* __restrict__ db2, const float* __restrict__ db3,
    const float* __restrict__ db4,
    float* __restrict__ out, int E)
{
    __shared__ float smem[128 * 64];
    int e = blockIdx.x * blockDim.x + threadIdx.x;
    if (e >= E) return;
    int tid = threadIdx.x;
    int lane = tid & 15;
    float* lbase = smem + tid * 64;

    int s = ei[e], d = ei[E + e];
    float zin[32];
    ld16(z + (size_t)s * 16, zin);
    ld16(z + (size_t)d * 16, zin + 16);

    const float* t0 = decw;
    const float* t1 = decw + 2048;
    const float* t2 = decw + 6144;
    const float* t3 = decw + 10240;
    const float* t4 = decw + 14336;

    // layer 0: 32 -> 64
    #pragma unroll 2
    for (int o = 0; o < 64; o++) {
        float acc = db0[o];
        const float4* w = (const float4*)(t0 + o * 32);
        #pragma unroll
        for (int q = 0; q < 8; q++) {
            float4 wv = w[q];
            acc += zin[q*4+0]*wv.x + zin[q*4+1]*wv.y + zin[q*4+2]*wv.z + zin[q*4+3]*wv.w;
        }
        lbase[(((o >> 2) ^ lane) << 2) | (o & 3)] = fmaxf(acc, 0.f);
    }
    dec_layer64(t1, db1, lbase, lane);
    dec_layer64(t2, db2, lbase, lane);
    dec_layer64(t3, db3, lbase, lane);

    // final 64 -> 8
    float a[64];
    #pragma unroll
    for (int q = 0; q < 16; q++) {
        float4 v = *(const float4*)(lbase + ((q ^ lane) << 2));
        a[q*4+0]=v.x; a[q*4+1]=v.y; a[q*4+2]=v.z; a[q*4+3]=v.w;
    }
    float r[8];
    #pragma unroll
    for (int j = 0; j < 8; j++) {
        float acc = db4[j];
        const float4* w = (const float4*)(t4 + j * 64);
        #pragma unroll
        for (int q = 0; q < 16; q++) {
            float4 wv = w[q];
            acc += a[q*4+0]*wv.x + a[q*4+1]*wv.y + a[q*4+2]*wv.z + a[q*4+3]*wv.w;
        }
        r[j] = acc;
    }
    float4* op = (float4*)(out + (size_t)e * 8);
    op[0] = make_float4(r[0], r[1], r[2], r[3]);
    op[1] = make_float4(r[4], r[5], r[6], r[7]);
}

// ---------------- launch ----------------
extern "C" void kernel_launch(void* const* d_in, const int* in_sizes, int n_in,
                              void* d_out, int out_size, void* d_ws, size_t ws_size,
                              hipStream_t stream)
{
    const float* x   = (const float*)d_in[0];
    const int*   ei  = (const int*)d_in[1];
    const float* ea  = (const float*)d_in[2];
    const float* eps = (const float*)d_in[3];
    const float* w1  = (const float*)d_in[4];
    const float* b1  = (const float*)d_in[5];
    const float* w2  = (const float*)d_in[6];
    const float* b2  = (const float*)d_in[7];
    const float* root[4]; const float* cb[4]; const float* g[4]; const float* be[4];
    for (int l = 0; l < 4; l++) {
        root[l] = (const float*)d_in[8 + 4*l];
        cb[l]   = (const float*)d_in[9 + 4*l];
        g[l]    = (const float*)d_in[10 + 4*l];
        be[l]   = (const float*)d_in[11 + 4*l];
    }
    const float* mu_w = (const float*)d_in[24];
    const float* mu_b = (const float*)d_in[25];
    const float* lv_w = (const float*)d_in[26];
    const float* lv_b = (const float*)d_in[27];
    const float* dw[5]; const float* db[5];
    for (int i = 0; i < 5; i++) {
        dw[i] = (const float*)d_in[28 + 2*i];
        db[i] = (const float*)d_in[29 + 2*i];
    }
    float* out = (float*)d_out;

    int N = in_sizes[0] / 16;
    int E = in_sizes[2] / 8;

    float* ws   = (float*)d_ws;
    float* agg  = ws;                          // N*16
    float* stats= ws + (size_t)N * 16;         // 32 (pad to 64)
    float* hbuf = stats + 64;                  // N*16
    float* h2   = hbuf + (size_t)N * 16;       // N*16
    float* zbuf = h2 + (size_t)N * 16;         // N*16
    float* decw = zbuf + (size_t)N * 16;       // 14848

    k_prep<<<(14848 + 255) / 256, 256, 0, stream>>>(dw[0], dw[1], dw[2], dw[3], dw[4], decw);

    for (int l = 0; l < 4; l++) {
        hipMemsetAsync(agg, 0, ((size_t)N * 16 + 64) * sizeof(float), stream);
        const float* hcur = (l == 0) ? x : hbuf;
        k_conv<<<(E/2 + 255) / 256, 256, 0, stream>>>(hcur, ei, ea, w1, b1, w2, b2, agg, E);
        k_node<<<(N*16 + 255) / 256, 256, 0, stream>>>(hcur, agg, root[l], cb[l], h2, stats, N);
        k_bn<<<(N*16 + 255) / 256, 256, 0, stream>>>(h2, stats, g[l], be[l], hbuf, N, 1.0f / N);
    }
    k_z<<<(N*16 + 255) / 256, 256, 0, stream>>>(hbuf, mu_w, mu_b, lv_w, lv_b, eps, zbuf, N);
    k_dec<<<(E + 127) / 128, 128, 0, stream>>>(zbuf, ei, decw, db[0], db[1], db[2], db[3], db[4], out, E);
}

// Round 2
// 1289.224 us; speedup vs baseline: 2.8781x; 2.8781x over previous
//
#include <hip/hip_runtime.h>
#include <math.h>

// ---------------- helpers ----------------
__device__ __forceinline__ void ld16(const float* __restrict__ p, float* a) {
    const float4* q = (const float4*)p;
    float4 v0 = q[0], v1 = q[1], v2 = q[2], v3 = q[3];
    a[0]=v0.x; a[1]=v0.y; a[2]=v0.z; a[3]=v0.w;
    a[4]=v1.x; a[5]=v1.y; a[6]=v1.z; a[7]=v1.w;
    a[8]=v2.x; a[9]=v2.y; a[10]=v2.z; a[11]=v2.w;
    a[12]=v3.x; a[13]=v3.y; a[14]=v3.z; a[15]=v3.w;
}

// ---------------- decoder weight transpose (once) ----------------
__global__ void k_prep(const float* __restrict__ dw0, const float* __restrict__ dw1,
                       const float* __restrict__ dw2, const float* __restrict__ dw3,
                       const float* __restrict__ dw4, float* __restrict__ t) {
    int i = blockIdx.x * blockDim.x + threadIdx.x;
    if (i < 2048)       { int r = i / 64, c = i % 64;          t[c*32 + r]          = dw0[i]; }
    else if (i < 6144)  { int j = i - 2048;  int r=j/64,c=j%64; t[2048  + c*64 + r] = dw1[j]; }
    else if (i < 10240) { int j = i - 6144;  int r=j/64,c=j%64; t[6144  + c*64 + r] = dw2[j]; }
    else if (i < 14336) { int j = i - 10240; int r=j/64,c=j%64; t[10240 + c*64 + r] = dw3[j]; }
    else if (i < 14848) { int j = i - 14336; int r=j/8, c=j%8;  t[14336 + c*64 + r] = dw4[j]; }
}

// ---------------- CSR build ----------------
__global__ __launch_bounds__(256) void k_count(const int* __restrict__ ei, int* __restrict__ cnt, int E) {
    int e = blockIdx.x * blockDim.x + threadIdx.x;
    if (e < E) atomicAdd(&cnt[ei[E + e]], 1);
}

// exclusive scan of 256-element blocks; bsum gets block totals
__global__ __launch_bounds__(256) void k_scanA(const int* __restrict__ cnt, int* __restrict__ offs,
                                               int* __restrict__ bsum, int N) {
    __shared__ int s[256];
    int i = blockIdx.x * 256 + threadIdx.x;
    int v = (i < N) ? cnt[i] : 0;
    s[threadIdx.x] = v;
    __syncthreads();
    #pragma unroll
    for (int d = 1; d < 256; d <<= 1) {
        int t = (threadIdx.x >= d) ? s[threadIdx.x - d] : 0;
        __syncthreads();
        s[threadIdx.x] += t;
        __syncthreads();
    }
    if (i < N) offs[i] = s[threadIdx.x] - v;            // exclusive
    if (threadIdx.x == 255) bsum[blockIdx.x] = s[255];  // block total
}

// exclusive scan of block totals (nb <= 256)
__global__ __launch_bounds__(256) void k_scanB(int* __restrict__ bsum, int nb) {
    __shared__ int s[256];
    int v = (threadIdx.x < nb) ? bsum[threadIdx.x] : 0;
    s[threadIdx.x] = v;
    __syncthreads();
    #pragma unroll
    for (int d = 1; d < 256; d <<= 1) {
        int t = (threadIdx.x >= d) ? s[threadIdx.x - d] : 0;
        __syncthreads();
        s[threadIdx.x] += t;
        __syncthreads();
    }
    if (threadIdx.x < nb) bsum[threadIdx.x] = s[threadIdx.x] - v;
}

__global__ __launch_bounds__(256) void k_scanC(int* __restrict__ offs, const int* __restrict__ bsum, int N) {
    int i = blockIdx.x * 256 + threadIdx.x;
    if (i < N) offs[i] += bsum[blockIdx.x];
}

__global__ __launch_bounds__(256) void k_fill(const int* __restrict__ ei, const int* __restrict__ offs,
                                              int* __restrict__ cursor, int* __restrict__ slotOf, int E) {
    int e = blockIdx.x * blockDim.x + threadIdx.x;
    if (e < E) {
        int d = ei[E + e];
        slotOf[e] = offs[d] + atomicAdd(&cursor[d], 1);
    }
}

// ---------------- conv edge kernel: msg -> CSR slot (no atomics) ----------------
__global__ __launch_bounds__(256) void k_conv(
    const float* __restrict__ h, const int* __restrict__ ei,
    const float* __restrict__ ea,
    const float* __restrict__ w1, const float* __restrict__ b1,
    const float* __restrict__ w2, const float* __restrict__ b2,
    const int* __restrict__ slotOf, float* __restrict__ msg, int E)
{
    int t = blockIdx.x * blockDim.x + threadIdx.x;
    int e0 = t * 2;
    if (e0 >= E) return;
    int e1 = e0 + 1;                       // E is even

    int s0 = ei[e0], s1 = ei[e1];

    // edge_attr rows (8 floats each)
    float ea0[8], ea1[8];
    {
        const float4* p = (const float4*)(ea + (size_t)e0 * 8);
        float4 v0 = p[0], v1 = p[1];
        ea0[0]=v0.x; ea0[1]=v0.y; ea0[2]=v0.z; ea0[3]=v0.w;
        ea0[4]=v1.x; ea0[5]=v1.y; ea0[6]=v1.z; ea0[7]=v1.w;
        const float4* q = (const float4*)(ea + (size_t)e1 * 8);
        float4 u0 = q[0], u1 = q[1];
        ea1[0]=u0.x; ea1[1]=u0.y; ea1[2]=u0.z; ea1[3]=u0.w;
        ea1[4]=u1.x; ea1[5]=u1.y; ea1[6]=u1.z; ea1[7]=u1.w;
    }

    float h0[16], h1[16];
    ld16(h + (size_t)s0 * 16, h0);
    ld16(h + (size_t)s1 * 16, h1);

    float m0[16], m1[16];
    #pragma unroll
    for (int q = 0; q < 16; q++) { m0[q] = 0.f; m1[q] = 0.f; }

    // msg[o] = sum_i hsrc[i] * ( b2[i*16+o] + sum_k hid[k]*w2[k*256+i*16+o] )
    #pragma unroll 1
    for (int k = 0; k < 16; k++) {
        float bk = b1[k];
        float a0 = bk, a1 = bk;
        #pragma unroll
        for (int j = 0; j < 8; j++) {
            float w = w1[j * 16 + k];
            a0 += ea0[j] * w;
            a1 += ea1[j] * w;
        }
        a0 = fmaxf(a0, 0.f);
        a1 = fmaxf(a1, 0.f);
        const float4* w4 = (const float4*)(w2 + k * 256);
        #pragma unroll
        for (int i = 0; i < 16; i++) {
            float s0v = a0 * h0[i];
            float s1v = a1 * h1[i];
            #pragma unroll
            for (int q = 0; q < 4; q++) {
                float4 w = w4[i * 4 + q];
                m0[q*4+0] += s0v * w.x; m0[q*4+1] += s0v * w.y;
                m0[q*4+2] += s0v * w.z; m0[q*4+3] += s0v * w.w;
                m1[q*4+0] += s1v * w.x; m1[q*4+1] += s1v * w.y;
                m1[q*4+2] += s1v * w.z; m1[q*4+3] += s1v * w.w;
            }
        }
    }
    // b2 term
    {
        const float4* b4 = (const float4*)b2;
        #pragma unroll
        for (int i = 0; i < 16; i++) {
            float s0v = h0[i];
            float s1v = h1[i];
            #pragma unroll
            for (int q = 0; q < 4; q++) {
                float4 w = b4[i * 4 + q];
                m0[q*4+0] += s0v * w.x; m0[q*4+1] += s0v * w.y;
                m0[q*4+2] += s0v * w.z; m0[q*4+3] += s0v * w.w;
                m1[q*4+0] += s1v * w.x; m1[q*4+1] += s1v * w.y;
                m1[q*4+2] += s1v * w.z; m1[q*4+3] += s1v * w.w;
            }
        }
    }

    int sl0 = slotOf[e0], sl1 = slotOf[e1];
    float4* p0 = (float4*)(msg + (size_t)sl0 * 16);
    p0[0] = make_float4(m0[0], m0[1], m0[2], m0[3]);
    p0[1] = make_float4(m0[4], m0[5], m0[6], m0[7]);
    p0[2] = make_float4(m0[8], m0[9], m0[10], m0[11]);
    p0[3] = make_float4(m0[12], m0[13], m0[14], m0[15]);
    float4* p1 = (float4*)(msg + (size_t)sl1 * 16);
    p1[0] = make_float4(m1[0], m1[1], m1[2], m1[3]);
    p1[1] = make_float4(m1[4], m1[5], m1[6], m1[7]);
    p1[2] = make_float4(m1[8], m1[9], m1[10], m1[11]);
    p1[3] = make_float4(m1[12], m1[13], m1[14], m1[15]);
}

// ---------------- node update: gather + root + bias + relu + BN stats ----------------
__global__ __launch_bounds__(256) void k_node(
    const float* __restrict__ h, const float* __restrict__ msg,
    const int* __restrict__ offs, const int* __restrict__ cnt,
    const float* __restrict__ root, const float* __restrict__ cb,
    float* __restrict__ h2, float* __restrict__ stats, int N)
{
    int t = blockIdx.x * blockDim.x + threadIdx.x;
    int n = t >> 4;
    int o = t & 15;
    float v = 0.f;
    if (n < N) {
        v = cb[o];
        int start = offs[n], deg = cnt[n];
        for (int j = 0; j < deg; j++)
            v += msg[(size_t)(start + j) * 16 + o];
        float hr[16];
        ld16(h + (size_t)n * 16, hr);
        #pragma unroll
        for (int i = 0; i < 16; i++) v += hr[i] * root[i * 16 + o];
        v = fmaxf(v, 0.f);
        h2[(size_t)n * 16 + o] = v;
    }
    __shared__ float ls[256];
    __shared__ float ls2[256];
    int tid = threadIdx.x;
    ls[tid] = v;
    ls2[tid] = v * v;
    __syncthreads();
    #pragma unroll
    for (int s = 128; s >= 16; s >>= 1) {
        if (tid < s) { ls[tid] += ls[tid + s]; ls2[tid] += ls2[tid + s]; }
        __syncthreads();
    }
    if (tid < 16) {
        atomicAdd(&stats[tid], ls[tid]);
        atomicAdd(&stats[16 + tid], ls2[tid]);
    }
}

// ---------------- BN apply ----------------
__global__ __launch_bounds__(256) void k_bn(
    const float* __restrict__ h2, const float* __restrict__ stats,
    const float* __restrict__ g, const float* __restrict__ be,
    float* __restrict__ hout, int N, float invN)
{
    int t = blockIdx.x * blockDim.x + threadIdx.x;
    if (t >= N * 16) return;
    int o = t & 15;
    float m = stats[o] * invN;
    float var = stats[16 + o] * invN - m * m;
    float sc = g[o] * rsqrtf(var + 1e-5f);
    hout[t] = (h2[t] - m) * sc + be[o];
}

// ---------------- mu / logvar / reparameterize ----------------
__global__ __launch_bounds__(256) void k_z(
    const float* __restrict__ h, const float* __restrict__ mu_w, const float* __restrict__ mu_b,
    const float* __restrict__ lv_w, const float* __restrict__ lv_b,
    const float* __restrict__ eps, float* __restrict__ z, int N)
{
    int t = blockIdx.x * blockDim.x + threadIdx.x;
    if (t >= N * 16) return;
    int n = t >> 4;
    int o = t & 15;
    float hr[16];
    ld16(h + (size_t)n * 16, hr);
    float mu = mu_b[o];
    float lv = lv_b[o];
    #pragma unroll
    for (int i = 0; i < 16; i++) {
        mu += hr[i] * mu_w[i * 16 + o];
        lv += hr[i] * lv_w[i * 16 + o];
    }
    lv = fminf(lv, 10.f);
    z[t] = mu + eps[t] * expf(0.5f * lv);
}

// ---------------- decoder ----------------
__device__ __forceinline__ void dec_layer64(const float* __restrict__ wt,
                                            const float* __restrict__ bias,
                                            float* lbase, int lane)
{
    float a[64];
    #pragma unroll
    for (int q = 0; q < 16; q++) {
        float4 v = *(const float4*)(lbase + ((q ^ lane) << 2));
        a[q*4+0]=v.x; a[q*4+1]=v.y; a[q*4+2]=v.z; a[q*4+3]=v.w;
    }
    #pragma unroll 2
    for (int o = 0; o < 64; o++) {
        float acc = bias[o];
        const float4* w = (const float4*)(wt + o * 64);
        #pragma unroll
        for (int q = 0; q < 16; q++) {
            float4 wv = w[q];
            acc += a[q*4+0]*wv.x + a[q*4+1]*wv.y + a[q*4+2]*wv.z + a[q*4+3]*wv.w;
        }
        lbase[(((o >> 2) ^ lane) << 2) | (o & 3)] = fmaxf(acc, 0.f);
    }
}

__global__ __launch_bounds__(128) void k_dec(
    const float* __restrict__ z, const int* __restrict__ ei,
    const float* __restrict__ decw,
    const float* __restrict__ db0, const float* __restrict__ db1,
    const float* __restrict__ db2, const float* __restrict__ db3,
    const float* __restrict__ db4,
    float* __restrict__ out, int E)
{
    __shared__ float smem[128 * 64];
    int e = blockIdx.x * blockDim.x + threadIdx.x;
    if (e >= E) return;
    int tid = threadIdx.x;
    int lane = tid & 15;
    float* lbase = smem + tid * 64;

    int s = ei[e], d = ei[E + e];
    float zin[32];
    ld16(z + (size_t)s * 16, zin);
    ld16(z + (size_t)d * 16, zin + 16);

    const float* t0 = decw;
    const float* t1 = decw + 2048;
    const float* t2 = decw + 6144;
    const float* t3 = decw + 10240;
    const float* t4 = decw + 14336;

    // layer 0: 32 -> 64
    #pragma unroll 2
    for (int o = 0; o < 64; o++) {
        float acc = db0[o];
        const float4* w = (const float4*)(t0 + o * 32);
        #pragma unroll
        for (int q = 0; q < 8; q++) {
            float4 wv = w[q];
            acc += zin[q*4+0]*wv.x + zin[q*4+1]*wv.y + zin[q*4+2]*wv.z + zin[q*4+3]*wv.w;
        }
        lbase[(((o >> 2) ^ lane) << 2) | (o & 3)] = fmaxf(acc, 0.f);
    }
    dec_layer64(t1, db1, lbase, lane);
    dec_layer64(t2, db2, lbase, lane);
    dec_layer64(t3, db3, lbase, lane);

    // final 64 -> 8
    float a[64];
    #pragma unroll
    for (int q = 0; q < 16; q++) {
        float4 v = *(const float4*)(lbase + ((q ^ lane) << 2));
        a[q*4+0]=v.x; a[q*4+1]=v.y; a[q*4+2]=v.z; a[q*4+3]=v.w;
    }
    float r[8];
    #pragma unroll
    for (int j = 0; j < 8; j++) {
        float acc = db4[j];
        const float4* w = (const float4*)(t4 + j * 64);
        #pragma unroll
        for (int q = 0; q < 16; q++) {
            float4 wv = w[q];
            acc += a[q*4+0]*wv.x + a[q*4+1]*wv.y + a[q*4+2]*wv.z + a[q*4+3]*wv.w;
        }
        r[j] = acc;
    }
    float4* op = (float4*)(out + (size_t)e * 8);
    op[0] = make_float4(r[0], r[1], r[2], r[3]);
    op[1] = make_float4(r[4], r[5], r[6], r[7]);
}

// ---------------- launch ----------------
extern "C" void kernel_launch(void* const* d_in, const int* in_sizes, int n_in,
                              void* d_out, int out_size, void* d_ws, size_t ws_size,
                              hipStream_t stream)
{
    const float* x   = (const float*)d_in[0];
    const int*   ei  = (const int*)d_in[1];
    const float* ea  = (const float*)d_in[2];
    const float* eps = (const float*)d_in[3];
    const float* w1  = (const float*)d_in[4];
    const float* b1  = (const float*)d_in[5];
    const float* w2  = (const float*)d_in[6];
    const float* b2  = (const float*)d_in[7];
    const float* root[4]; const float* cb[4]; const float* g[4]; const float* be[4];
    for (int l = 0; l < 4; l++) {
        root[l] = (const float*)d_in[8 + 4*l];
        cb[l]   = (const float*)d_in[9 + 4*l];
        g[l]    = (const float*)d_in[10 + 4*l];
        be[l]   = (const float*)d_in[11 + 4*l];
    }
    const float* mu_w = (const float*)d_in[24];
    const float* mu_b = (const float*)d_in[25];
    const float* lv_w = (const float*)d_in[26];
    const float* lv_b = (const float*)d_in[27];
    const float* dw[5]; const float* db[5];
    for (int i = 0; i < 5; i++) {
        dw[i] = (const float*)d_in[28 + 2*i];
        db[i] = (const float*)d_in[29 + 2*i];
    }
    float* out = (float*)d_out;

    int N = in_sizes[0] / 16;
    int E = in_sizes[2] / 8;

    // ---- workspace layout ----
    int*   cnt    = (int*)d_ws;                  // N
    int*   cursor = cnt + N;                     // N
    int*   offs   = cursor + N;                  // N
    int*   bsum   = offs + N;                    // 256
    int*   slotOf = bsum + 256;                  // E
    float* stats  = (float*)(slotOf + E);        // 64
    float* msg    = stats + 64;                  // E*16
    float* hbuf   = msg + (size_t)E * 16;        // N*16
    float* h2     = hbuf + (size_t)N * 16;       // N*16
    float* zbuf   = h2 + (size_t)N * 16;         // N*16
    float* decw   = zbuf + (size_t)N * 16;       // 14848

    int nbScan = (N + 255) / 256;                // 196 for N=50000 (must be <=256)

    k_prep<<<(14848 + 255) / 256, 256, 0, stream>>>(dw[0], dw[1], dw[2], dw[3], dw[4], decw);

    // ---- CSR build (once; reused by all 4 conv layers) ----
    hipMemsetAsync(cnt, 0, (size_t)2 * N * sizeof(int), stream);   // cnt + cursor
    k_count<<<(E + 255) / 256, 256, 0, stream>>>(ei, cnt, E);
    k_scanA<<<nbScan, 256, 0, stream>>>(cnt, offs, bsum, N);
    k_scanB<<<1, 256, 0, stream>>>(bsum, nbScan);
    k_scanC<<<nbScan, 256, 0, stream>>>(offs, bsum, N);
    k_fill<<<(E + 255) / 256, 256, 0, stream>>>(ei, offs, cursor, slotOf, E);

    for (int l = 0; l < 4; l++) {
        hipMemsetAsync(stats, 0, 64 * sizeof(float), stream);
        const float* hcur = (l == 0) ? x : hbuf;
        k_conv<<<(E/2 + 255) / 256, 256, 0, stream>>>(hcur, ei, ea, w1, b1, w2, b2, slotOf, msg, E);
        k_node<<<(N*16 + 255) / 256, 256, 0, stream>>>(hcur, msg, offs, cnt, root[l], cb[l], h2, stats, N);
        k_bn<<<(N*16 + 255) / 256, 256, 0, stream>>>(h2, stats, g[l], be[l], hbuf, N, 1.0f / N);
    }
    k_z<<<(N*16 + 255) / 256, 256, 0, stream>>>(hbuf, mu_w, mu_b, lv_w, lv_b, eps, zbuf, N);
    k_dec<<<(E + 127) / 128, 128, 0, stream>>>(zbuf, ei, decw, db[0], db[1], db[2], db[3], db[4], out, E);
}